// Round 4
// baseline (460.165 us; speedup 1.0000x reference)
//
#include <hip/hip_runtime.h>
#include <math.h>
#include <stdint.h>

#define N_NODES 50000
#define N_EDGES 800000
#define N_TOT   850000
#define IN_F    191
#define F1      256
#define NH1     16
#define NC1     16
#define F2      24
#define NH2     8
#define NC2     3
#define KP      224          // K padded to 7*32
#define MPAD    50048        // 391*128
#define NCVT_X  (MPAD * 28)
#define NCVT_W  (F1 * 28)

typedef __attribute__((ext_vector_type(8))) short bf16x8;
typedef __attribute__((ext_vector_type(4))) float f32x4;

#define GLL16(g, s) __builtin_amdgcn_global_load_lds( \
    (const __attribute__((address_space(1))) void*)(g), \
    (__attribute__((address_space(3))) void*)(s), 16, 0, 0)

__device__ __forceinline__ float lrelu(float x) { return x > 0.f ? x : 0.2f * x; }

__device__ __forceinline__ uint16_t f2bf1(float f) {
    uint32_t u = __float_as_uint(f);
    return (uint16_t)((u + 0x7fffu + ((u >> 16) & 1u)) >> 16);
}
__device__ __forceinline__ uint16_t f2bf(float f, float* back) {
    uint32_t u = __float_as_uint(f);
    uint32_t r = (u + 0x7fffu + ((u >> 16) & 1u)) >> 16;
    *back = __uint_as_float(r << 16);
    return (uint16_t)r;
}
__device__ __forceinline__ void bf2f2(uint32_t u, float* lo, float* hi) {
    *lo = __uint_as_float(u << 16);
    *hi = __uint_as_float(u & 0xffff0000u);
}

// ---------------- fused: in-degree histogram + edge_attr sum ----------------
__global__ void k_hist_easum(const int* __restrict__ ei, const float* __restrict__ ea,
                             int* counts, float* scalars) {
    int i = blockIdx.x * blockDim.x + threadIdx.x;
    float v = 0.f;
    if (i < N_EDGES) {
        atomicAdd(&counts[ei[N_EDGES + i]], 1);
        v = ea[i];
    }
    #pragma unroll
    for (int off = 32; off >= 1; off >>= 1) v += __shfl_xor(v, off);
    if ((threadIdx.x & 63) == 0) atomicAdd(&scalars[25], v);
}

// ---------------- we_dot per head + ea_mean ----------------
__global__ void k_wedot(const float* __restrict__ We1, const float* __restrict__ ae1,
                        const float* __restrict__ We2, const float* __restrict__ ae2,
                        float* scalars) {
    int t = threadIdx.x;
    if (t < NH1) {
        float s = 0.f;
        for (int c = 0; c < NC1; c++) s += We1[t * NC1 + c] * ae1[t * NC1 + c];
        scalars[1 + t] = s;
    } else if (t < NH1 + NH2) {
        int h = t - NH1;
        float s = 0.f;
        for (int c = 0; c < NC2; c++) s += We2[h * NC2 + c] * ae2[h * NC2 + c];
        scalars[17 + h] = s;
    } else if (t == 63) {
        scalars[0] = scalars[25] / (float)N_EDGES;   // ea_mean
    }
}

// ---------------- hierarchical scan, stage 1: per-block (1024) scan ----------------
// value scanned = counts[i] + 1  (the +1 is the self loop)
__global__ __launch_bounds__(1024) void k_scan1(const int* __restrict__ counts,
                                                int* rowptr, int* bsums) {
    __shared__ int wsum[16];
    int t = threadIdx.x;
    int lane = t & 63, w = t >> 6;
    int i = blockIdx.x * 1024 + t;
    int v = (i < N_NODES) ? counts[i] + 1 : 0;
    int incl = v;
    #pragma unroll
    for (int off = 1; off < 64; off <<= 1) {
        int u = __shfl_up(incl, off);
        if (lane >= off) incl += u;
    }
    if (lane == 63) wsum[w] = incl;
    __syncthreads();
    int woff = 0;
    #pragma unroll
    for (int k = 0; k < 16; k++) woff += (k < w) ? wsum[k] : 0;
    if (i < N_NODES) rowptr[i] = woff + incl - v;
    if (t == 1023) bsums[blockIdx.x] = woff + incl;
}

// ---------------- scan stage 2: add block prefix, write cursor + rowptr[N] ----------------
__global__ __launch_bounds__(1024) void k_scan2(int* rowptr, int* cursor,
                                                const int* __restrict__ bsums) {
    __shared__ int off_s;
    int b = blockIdx.x, t = threadIdx.x;
    if (t == 0) {
        int o = 0;
        for (int k = 0; k < b; k++) o += bsums[k];
        off_s = o;
        if (b == 48) rowptr[N_NODES] = o + bsums[48];
    }
    __syncthreads();
    int i = b * 1024 + t;
    if (i < N_NODES) {
        int r = rowptr[i] + off_s;
        rowptr[i] = r;
        cursor[i] = r;
    }
}

// ---------------- scatter edges (+self loops) into CSR ----------------
__global__ void k_scatter(const int* __restrict__ ei, const float* __restrict__ ea,
                          const float* __restrict__ scalars, int* cursor,
                          int* csr_src, float* csr_ea) {
    int i = blockIdx.x * blockDim.x + threadIdx.x;
    if (i < N_EDGES) {
        int s = ei[i], d = ei[N_EDGES + i];
        int pos = atomicAdd(&cursor[d], 1);
        csr_src[pos] = s;
        csr_ea[pos] = ea[i];
    } else if (i < N_TOT) {
        int n = i - N_EDGES;
        int pos = atomicAdd(&cursor[n], 1);
        csr_src[pos] = n;
        csr_ea[pos] = scalars[0];
    }
}

// ---------------- fused convert: x -> (xh, xl) [MPAD][KP], W1 -> (whT, wlT) [F1][KP] ----------------
__global__ void k_cvt(const float* __restrict__ x, const float* __restrict__ W1,
                      uint16_t* __restrict__ xh, uint16_t* __restrict__ xl,
                      uint16_t* __restrict__ wht, uint16_t* __restrict__ wlt) {
    int idx = blockIdx.x * 256 + threadIdx.x;
    if (idx < NCVT_X) {
        int row = idx / 28, kw = idx - row * 28;
        int k0 = kw * 8;
        uint16_t hv[8], lv[8];
        #pragma unroll
        for (int j = 0; j < 8; j++) {
            int k = k0 + j;
            float v = (row < N_NODES && k < IN_F) ? x[(size_t)row * IN_F + k] : 0.f;
            float hf;
            hv[j] = f2bf(v, &hf);
            lv[j] = f2bf1(v - hf);
        }
        *(uint4*)(xh + (size_t)row * KP + k0) = *(const uint4*)hv;
        *(uint4*)(xl + (size_t)row * KP + k0) = *(const uint4*)lv;
    } else if (idx < NCVT_X + NCVT_W) {
        int id2 = idx - NCVT_X;
        int col = id2 / 28, kw = id2 - col * 28;
        int k0 = kw * 8;
        uint16_t hv[8], lv[8];
        #pragma unroll
        for (int j = 0; j < 8; j++) {
            int k = k0 + j;
            float v = (k < IN_F) ? W1[(size_t)k * F1 + col] : 0.f;
            float hf;
            hv[j] = f2bf(v, &hf);
            lv[j] = f2bf1(v - hf);
        }
        *(uint4*)(wht + (size_t)col * KP + k0) = *(const uint4*)hv;
        *(uint4*)(wlt + (size_t)col * KP + k0) = *(const uint4*)lv;
    }
}

// ---------------- GEMM1 via MFMA: xl1 = x @ W1, bf16 hi/lo split (3 terms) ----------------
__global__ __launch_bounds__(256) void k_gemm1_mfma(const uint16_t* __restrict__ xh,
        const uint16_t* __restrict__ xl, const uint16_t* __restrict__ wht,
        const uint16_t* __restrict__ wlt, uint16_t* __restrict__ xl1b) {
    __shared__ uint16_t lds[4 * 8 * 64 * 8];   // Ah, Al, Bh, Bl ; 32 KiB
    const int t = threadIdx.x;
    const int l = t & 63, w = t >> 6;
    const int wm = w >> 1, wn = w & 1;
    const int m0 = blockIdx.x * 128;
    const int n0 = blockIdx.y * 128;
    const int lr = l & 15, lk = l >> 4;

    uint16_t* ldsAh = lds;
    uint16_t* ldsAl = lds + 8 * 64 * 8;
    uint16_t* ldsBh = lds + 2 * 8 * 64 * 8;
    uint16_t* ldsBl = lds + 3 * 8 * 64 * 8;

    f32x4 acc[4][4];
    #pragma unroll
    for (int i = 0; i < 4; i++)
        #pragma unroll
        for (int j = 0; j < 4; j++)
            acc[i][j] = (f32x4){0.f, 0.f, 0.f, 0.f};

    for (int ks = 0; ks < 7; ks++) {
        const int kb = ks * 32 + lk * 8;
        #pragma unroll
        for (int ii = 0; ii < 2; ii++) {
            const int f = 2 * w + ii;
            const uint16_t* sAh = xh  + (size_t)(m0 + f * 16 + lr) * KP + kb;
            const uint16_t* sAl = xl  + (size_t)(m0 + f * 16 + lr) * KP + kb;
            const uint16_t* sBh = wht + (size_t)(n0 + f * 16 + lr) * KP + kb;
            const uint16_t* sBl = wlt + (size_t)(n0 + f * 16 + lr) * KP + kb;
            GLL16(sAh, ldsAh + f * 512);
            GLL16(sAl, ldsAl + f * 512);
            GLL16(sBh, ldsBh + f * 512);
            GLL16(sBl, ldsBl + f * 512);
        }
        __syncthreads();
        bf16x8 ah[4], al[4];
        #pragma unroll
        for (int i = 0; i < 4; i++) {
            const int f = wm * 4 + i;
            ah[i] = *(const bf16x8*)(ldsAh + (f * 64 + l) * 8);
            al[i] = *(const bf16x8*)(ldsAl + (f * 64 + l) * 8);
        }
        #pragma unroll
        for (int j = 0; j < 4; j++) {
            const int g = wn * 4 + j;
            bf16x8 bh = *(const bf16x8*)(ldsBh + (g * 64 + l) * 8);
            bf16x8 bl = *(const bf16x8*)(ldsBl + (g * 64 + l) * 8);
            #pragma unroll
            for (int i = 0; i < 4; i++) {
                acc[i][j] = __builtin_amdgcn_mfma_f32_16x16x32_bf16(ah[i], bh, acc[i][j], 0, 0, 0);
                acc[i][j] = __builtin_amdgcn_mfma_f32_16x16x32_bf16(ah[i], bl, acc[i][j], 0, 0, 0);
                acc[i][j] = __builtin_amdgcn_mfma_f32_16x16x32_bf16(al[i], bh, acc[i][j], 0, 0, 0);
            }
        }
        __syncthreads();
    }
    #pragma unroll
    for (int i = 0; i < 4; i++) {
        const int gm_base = m0 + wm * 64 + i * 16 + lk * 4;
        #pragma unroll
        for (int r = 0; r < 4; r++) {
            const int gm = gm_base + r;
            if (gm < N_NODES) {
                #pragma unroll
                for (int j = 0; j < 4; j++) {
                    const int gn = n0 + wn * 64 + j * 16 + lr;
                    xl1b[(size_t)gm * F1 + gn] = f2bf1(acc[i][j][r]);
                }
            }
        }
    }
}

// ---------------- alpha_src1/alpha_dst1 (bf16 xl1) ----------------
__global__ void k_alphas1(const uint16_t* __restrict__ xl1b, const float* __restrict__ a_src,
                          const float* __restrict__ a_dst,
                          float* __restrict__ asrc, float* __restrict__ adst) {
    int idx = blockIdx.x * blockDim.x + threadIdx.x;   // n*16 + h
    if (idx >= N_NODES * NH1) return;
    int h = idx & 15;
    const uint4* xp = (const uint4*)(xl1b + (size_t)idx * 16);
    uint4 u0 = xp[0], u1 = xp[1];
    uint32_t us[8] = {u0.x, u0.y, u0.z, u0.w, u1.x, u1.y, u1.z, u1.w};
    float as = 0.f, ad = 0.f;
    #pragma unroll
    for (int q = 0; q < 8; q++) {
        float lo, hi;
        bf2f2(us[q], &lo, &hi);
        as += lo * a_src[h * 16 + 2 * q] + hi * a_src[h * 16 + 2 * q + 1];
        ad += lo * a_dst[h * 16 + 2 * q] + hi * a_dst[h * 16 + 2 * q + 1];
    }
    asrc[idx] = as;
    adst[idx] = ad;
}

// ---------------- aggregation layer 1 (wave per node, 2x unrolled edge loop) ----------------
__global__ __launch_bounds__(256) void k_agg1(const int* __restrict__ rowptr,
        const int* __restrict__ csr_src, const float* __restrict__ csr_ea,
        const uint16_t* __restrict__ xl1b, const float* __restrict__ asrc,
        const float* __restrict__ adst, const float* __restrict__ scalars,
        const float* __restrict__ b1, uint16_t* __restrict__ h1b) {
    int node = blockIdx.x * 4 + (threadIdx.x >> 6);
    int lane = threadIdx.x & 63;
    int eg = lane >> 4, h = lane & 15;
    int r0 = rowptr[node], r1 = rowptr[node + 1];
    float ad = adst[node * 16 + h];
    float wd = scalars[1 + h];
    float den = 0.f;
    float acc[16];
    #pragma unroll
    for (int c = 0; c < 16; c++) acc[c] = 0.f;
    int j = r0 + eg;
    for (; j + 4 < r1; j += 8) {
        int s0 = csr_src[j], s1 = csr_src[j + 4];
        float e0 = csr_ea[j], e1 = csr_ea[j + 4];
        float p0 = asrc[s0 * 16 + h], p1 = asrc[s1 * 16 + h];
        const uint4* xp0 = (const uint4*)(xl1b + (size_t)s0 * F1 + h * 16);
        const uint4* xp1 = (const uint4*)(xl1b + (size_t)s1 * F1 + h * 16);
        uint4 u0a = xp0[0], u0b = xp0[1];
        uint4 u1a = xp1[0], u1b = xp1[1];
        float w0 = __expf(lrelu(p0 + ad + e0 * wd));
        float w1 = __expf(lrelu(p1 + ad + e1 * wd));
        den += w0 + w1;
        float lo, hi;
        bf2f2(u0a.x, &lo, &hi); acc[0] += w0 * lo;  acc[1] += w0 * hi;
        bf2f2(u0a.y, &lo, &hi); acc[2] += w0 * lo;  acc[3] += w0 * hi;
        bf2f2(u0a.z, &lo, &hi); acc[4] += w0 * lo;  acc[5] += w0 * hi;
        bf2f2(u0a.w, &lo, &hi); acc[6] += w0 * lo;  acc[7] += w0 * hi;
        bf2f2(u0b.x, &lo, &hi); acc[8] += w0 * lo;  acc[9] += w0 * hi;
        bf2f2(u0b.y, &lo, &hi); acc[10] += w0 * lo; acc[11] += w0 * hi;
        bf2f2(u0b.z, &lo, &hi); acc[12] += w0 * lo; acc[13] += w0 * hi;
        bf2f2(u0b.w, &lo, &hi); acc[14] += w0 * lo; acc[15] += w0 * hi;
        bf2f2(u1a.x, &lo, &hi); acc[0] += w1 * lo;  acc[1] += w1 * hi;
        bf2f2(u1a.y, &lo, &hi); acc[2] += w1 * lo;  acc[3] += w1 * hi;
        bf2f2(u1a.z, &lo, &hi); acc[4] += w1 * lo;  acc[5] += w1 * hi;
        bf2f2(u1a.w, &lo, &hi); acc[6] += w1 * lo;  acc[7] += w1 * hi;
        bf2f2(u1b.x, &lo, &hi); acc[8] += w1 * lo;  acc[9] += w1 * hi;
        bf2f2(u1b.y, &lo, &hi); acc[10] += w1 * lo; acc[11] += w1 * hi;
        bf2f2(u1b.z, &lo, &hi); acc[12] += w1 * lo; acc[13] += w1 * hi;
        bf2f2(u1b.w, &lo, &hi); acc[14] += w1 * lo; acc[15] += w1 * hi;
    }
    if (j < r1) {
        int s = csr_src[j];
        float a = lrelu(asrc[s * 16 + h] + ad + csr_ea[j] * wd);
        float wgt = __expf(a);
        den += wgt;
        const uint4* xp = (const uint4*)(xl1b + (size_t)s * F1 + h * 16);
        uint4 u0 = xp[0], u1 = xp[1];
        float lo, hi;
        bf2f2(u0.x, &lo, &hi); acc[0] += wgt * lo;  acc[1] += wgt * hi;
        bf2f2(u0.y, &lo, &hi); acc[2] += wgt * lo;  acc[3] += wgt * hi;
        bf2f2(u0.z, &lo, &hi); acc[4] += wgt * lo;  acc[5] += wgt * hi;
        bf2f2(u0.w, &lo, &hi); acc[6] += wgt * lo;  acc[7] += wgt * hi;
        bf2f2(u1.x, &lo, &hi); acc[8] += wgt * lo;  acc[9] += wgt * hi;
        bf2f2(u1.y, &lo, &hi); acc[10] += wgt * lo; acc[11] += wgt * hi;
        bf2f2(u1.z, &lo, &hi); acc[12] += wgt * lo; acc[13] += wgt * hi;
        bf2f2(u1.w, &lo, &hi); acc[14] += wgt * lo; acc[15] += wgt * hi;
    }
    den += __shfl_xor(den, 16);
    den += __shfl_xor(den, 32);
    float inv = 1.f / (den + 1e-16f);
    #pragma unroll
    for (int c = 0; c < 16; c++) {
        acc[c] += __shfl_xor(acc[c], 16);
        acc[c] += __shfl_xor(acc[c], 32);
    }
    if (eg == 0) {
        uint32_t pk[8];
        #pragma unroll
        for (int q = 0; q < 8; q++) {
            float v0 = acc[2 * q] * inv + b1[h * 16 + 2 * q];
            float v1 = acc[2 * q + 1] * inv + b1[h * 16 + 2 * q + 1];
            v0 = v0 > 0.f ? v0 : expm1f(v0);   // ELU
            v1 = v1 > 0.f ? v1 : expm1f(v1);
            pk[q] = (uint32_t)f2bf1(v0) | ((uint32_t)f2bf1(v1) << 16);
        }
        uint4* op = (uint4*)(h1b + (size_t)node * F1 + h * 16);
        op[0] = make_uint4(pk[0], pk[1], pk[2], pk[3]);
        op[1] = make_uint4(pk[4], pk[5], pk[6], pk[7]);
    }
}

// ---------------- GEMM2: xl2 = h1 @ W2, output bf16 padded [n][8][4] ----------------
__global__ __launch_bounds__(256) void k_gemm2(const uint16_t* __restrict__ h1b,
                                               const float* __restrict__ W2,
                                               uint16_t* __restrict__ xl2b) {
    __shared__ float W2t[F2][260];
    int t = threadIdx.x;
    for (int i = t; i < 256 * F2; i += 256) {
        int k = i / F2, c = i - k * F2;
        W2t[c][k] = W2[i];
    }
    __syncthreads();
    int idx = blockIdx.x * 256 + t;
    if (idx >= N_NODES * F2) return;
    int n = idx / F2, col = idx - n * F2;
    const uint4* hp = (const uint4*)(h1b + (size_t)n * F1);
    float acc = 0.f;
    #pragma unroll 4
    for (int q = 0; q < 32; q++) {
        uint4 u = hp[q];
        const float4* wp = (const float4*)(&W2t[col][q * 8]);
        float4 w0 = wp[0], w1 = wp[1];
        float lo, hi;
        bf2f2(u.x, &lo, &hi); acc += lo * w0.x + hi * w0.y;
        bf2f2(u.y, &lo, &hi); acc += lo * w0.z + hi * w0.w;
        bf2f2(u.z, &lo, &hi); acc += lo * w1.x + hi * w1.y;
        bf2f2(u.w, &lo, &hi); acc += lo * w1.z + hi * w1.w;
    }
    int hh = col / 3, cc = col - hh * 3;
    xl2b[(size_t)n * 32 + hh * 4 + cc] = f2bf1(acc);
}

// ---------------- zero the padded channel of xl2b ----------------
__global__ void k_xl2pad(uint16_t* __restrict__ xl2b) {
    int i = blockIdx.x * 256 + threadIdx.x;    // n*8 + h
    if (i < N_NODES * 8) xl2b[(size_t)i * 4 + 3] = 0;
}

// ---------------- alpha_src2/alpha_dst2 (bf16 xl2) ----------------
__global__ void k_alphas2(const uint16_t* __restrict__ xl2b, const float* __restrict__ a_src,
                          const float* __restrict__ a_dst,
                          float* __restrict__ asrc, float* __restrict__ adst) {
    int idx = blockIdx.x * blockDim.x + threadIdx.x;   // n*8 + h
    if (idx >= N_NODES * NH2) return;
    int h = idx & 7;
    const uint2* xp = (const uint2*)(xl2b + (size_t)idx * 4);
    uint2 u = xp[0];
    float x0, x1, x2, dummy;
    bf2f2(u.x, &x0, &x1);
    bf2f2(u.y, &x2, &dummy);
    asrc[idx] = x0 * a_src[h * 3 + 0] + x1 * a_src[h * 3 + 1] + x2 * a_src[h * 3 + 2];
    adst[idx] = x0 * a_dst[h * 3 + 0] + x1 * a_dst[h * 3 + 1] + x2 * a_dst[h * 3 + 2];
}

// ---------------- aggregation layer 2 (wave per node, mean over heads) ----------------
__global__ __launch_bounds__(256) void k_agg2(const int* __restrict__ rowptr,
        const int* __restrict__ csr_src, const float* __restrict__ csr_ea,
        const uint16_t* __restrict__ xl2b, const float* __restrict__ asrc,
        const float* __restrict__ adst, const float* __restrict__ scalars,
        const float* __restrict__ b2, float* __restrict__ out) {
    int node = blockIdx.x * 4 + (threadIdx.x >> 6);
    int lane = threadIdx.x & 63;
    int eg = lane >> 3, h = lane & 7;
    int r0 = rowptr[node], r1 = rowptr[node + 1];
    float ad = adst[node * 8 + h];
    float wd = scalars[17 + h];
    float den = 0.f, a0 = 0.f, a1 = 0.f, a2 = 0.f;
    for (int j = r0 + eg; j < r1; j += 8) {
        int s = csr_src[j];
        float a = lrelu(asrc[s * 8 + h] + ad + csr_ea[j] * wd);
        float wgt = __expf(a);
        den += wgt;
        const uint2* xp = (const uint2*)(xl2b + ((size_t)s * 8 + h) * 4);
        uint2 u = xp[0];
        float x0, x1, x2, dummy;
        bf2f2(u.x, &x0, &x1);
        bf2f2(u.y, &x2, &dummy);
        a0 += wgt * x0;
        a1 += wgt * x1;
        a2 += wgt * x2;
    }
    den += __shfl_xor(den, 8); den += __shfl_xor(den, 16); den += __shfl_xor(den, 32);
    float inv = 1.f / (den + 1e-16f);
    a0 += __shfl_xor(a0, 8); a0 += __shfl_xor(a0, 16); a0 += __shfl_xor(a0, 32);
    a1 += __shfl_xor(a1, 8); a1 += __shfl_xor(a1, 16); a1 += __shfl_xor(a1, 32);
    a2 += __shfl_xor(a2, 8); a2 += __shfl_xor(a2, 16); a2 += __shfl_xor(a2, 32);
    a0 *= inv; a1 *= inv; a2 *= inv;
    a0 += __shfl_xor(a0, 1); a0 += __shfl_xor(a0, 2); a0 += __shfl_xor(a0, 4);
    a1 += __shfl_xor(a1, 1); a1 += __shfl_xor(a1, 2); a1 += __shfl_xor(a1, 4);
    a2 += __shfl_xor(a2, 1); a2 += __shfl_xor(a2, 2); a2 += __shfl_xor(a2, 4);
    if (lane == 0) {
        float v0 = a0 * 0.125f + b2[0];
        float v1 = a1 * 0.125f + b2[1];
        float v2 = a2 * 0.125f + b2[2];
        out[node * 3 + 0] = v0 > 0.f ? v0 : expm1f(v0);
        out[node * 3 + 1] = v1 > 0.f ? v1 : expm1f(v1);
        out[node * 3 + 2] = v2 > 0.f ? v2 : expm1f(v2);
    }
}

extern "C" void kernel_launch(void* const* d_in, const int* in_sizes, int n_in,
                              void* d_out, int out_size, void* d_ws, size_t ws_size,
                              hipStream_t stream) {
    const float* x       = (const float*)d_in[0];
    const int*   ei      = (const int*)d_in[1];
    const float* ea      = (const float*)d_in[2];
    const float* W1      = (const float*)d_in[3];
    const float* We1     = (const float*)d_in[4];
    const float* a_src1  = (const float*)d_in[5];
    const float* a_dst1  = (const float*)d_in[6];
    const float* a_edge1 = (const float*)d_in[7];
    const float* b1      = (const float*)d_in[8];
    const float* W2      = (const float*)d_in[9];
    const float* We2     = (const float*)d_in[10];
    const float* a_src2  = (const float*)d_in[11];
    const float* a_dst2  = (const float*)d_in[12];
    const float* a_edge2 = (const float*)d_in[13];
    const float* b2      = (const float*)d_in[14];
    float* out = (float*)d_out;

    char* ws = (char*)d_ws;
    size_t off = 0;
    auto alloc = [&](size_t nbytes) -> void* {
        void* p = ws + off;
        off = (off + nbytes + 255) & ~(size_t)255;
        return p;
    };
    uint16_t* xl1b = (uint16_t*)alloc((size_t)N_NODES * F1 * 2);
    uint16_t* h1b  = (uint16_t*)alloc((size_t)N_NODES * F1 * 2);
    float* asrc1   = (float*)alloc((size_t)N_NODES * NH1 * 4);
    float* adst1   = (float*)alloc((size_t)N_NODES * NH1 * 4);
    uint16_t* xl2b = (uint16_t*)alloc((size_t)N_NODES * 32 * 2);
    float* asrc2   = (float*)alloc((size_t)N_NODES * NH2 * 4);
    float* adst2   = (float*)alloc((size_t)N_NODES * NH2 * 4);
    int*   counts  = (int*)alloc((size_t)N_NODES * 4);
    int*   rowptr  = (int*)alloc((size_t)(N_NODES + 1) * 4);
    int*   cursor  = (int*)alloc((size_t)N_NODES * 4);
    int*   bsums   = (int*)alloc(64 * 4);
    int*   csr_src = (int*)alloc((size_t)N_TOT * 4);
    float* csr_ea  = (float*)alloc((size_t)N_TOT * 4);
    float* scalars = (float*)alloc(128);
    uint16_t* wht  = (uint16_t*)alloc((size_t)F1 * KP * 2);
    uint16_t* wlt  = (uint16_t*)alloc((size_t)F1 * KP * 2);
    uint16_t* xh   = (uint16_t*)alloc((size_t)MPAD * KP * 2);
    uint16_t* xlo  = (uint16_t*)alloc((size_t)MPAD * KP * 2);

    hipMemsetAsync(counts, 0, (size_t)N_NODES * 4, stream);
    hipMemsetAsync(scalars, 0, 128, stream);
    hipLaunchKernelGGL(k_hist_easum, dim3((N_EDGES + 255) / 256), dim3(256), 0, stream,
                       ei, ea, counts, scalars);
    hipLaunchKernelGGL(k_wedot, dim3(1), dim3(64), 0, stream,
                       We1, a_edge1, We2, a_edge2, scalars);
    hipLaunchKernelGGL(k_scan1, dim3(49), dim3(1024), 0, stream, counts, rowptr, bsums);
    hipLaunchKernelGGL(k_scan2, dim3(49), dim3(1024), 0, stream, rowptr, cursor, bsums);
    hipLaunchKernelGGL(k_scatter, dim3((N_TOT + 255) / 256), dim3(256), 0, stream,
                       ei, ea, scalars, cursor, csr_src, csr_ea);
    hipLaunchKernelGGL(k_cvt, dim3((NCVT_X + NCVT_W + 255) / 256), dim3(256), 0, stream,
                       x, W1, xh, xlo, wht, wlt);
    hipLaunchKernelGGL(k_gemm1_mfma, dim3(MPAD / 128, 2), dim3(256), 0, stream,
                       xh, xlo, wht, wlt, xl1b);
    hipLaunchKernelGGL(k_alphas1, dim3((N_NODES * NH1 + 255) / 256), dim3(256), 0, stream,
                       xl1b, a_src1, a_dst1, asrc1, adst1);
    hipLaunchKernelGGL(k_agg1, dim3(N_NODES / 4), dim3(256), 0, stream,
                       rowptr, csr_src, csr_ea, xl1b, asrc1, adst1, scalars, b1, h1b);
    hipLaunchKernelGGL(k_xl2pad, dim3((N_NODES * 8 + 255) / 256), dim3(256), 0, stream,
                       xl2b);
    hipLaunchKernelGGL(k_gemm2, dim3((N_NODES * F2 + 255) / 256), dim3(256), 0, stream,
                       h1b, W2, xl2b);
    hipLaunchKernelGGL(k_alphas2, dim3((N_NODES * NH2 + 255) / 256), dim3(256), 0, stream,
                       xl2b, a_src2, a_dst2, asrc2, adst2);
    hipLaunchKernelGGL(k_agg2, dim3(N_NODES / 4), dim3(256), 0, stream,
                       rowptr, csr_src, csr_ea, xl2b, asrc2, adst2, scalars, b2, out);
}

// Round 5
// 326.372 us; speedup vs baseline: 1.4099x; 1.4099x over previous
//
#include <hip/hip_runtime.h>
#include <math.h>
#include <stdint.h>

#define N_NODES 50000
#define N_EDGES 800000
#define N_TOT   850000
#define IN_F    191
#define F1      256
#define NH1     16
#define NC1     16
#define F2      24
#define NH2     8
#define NC2     3
#define KP      224          // K padded to 7*32
#define MPAD    50048        // 391*128
#define NCVT_X  (MPAD * 28)
#define NCVT_W  (F1 * 28)

typedef __attribute__((ext_vector_type(8))) short bf16x8;
typedef __attribute__((ext_vector_type(4))) float f32x4;

#define GLL16(g, s) __builtin_amdgcn_global_load_lds( \
    (const __attribute__((address_space(1))) void*)(g), \
    (__attribute__((address_space(3))) void*)(s), 16, 0, 0)

__device__ __forceinline__ float lrelu(float x) { return x > 0.f ? x : 0.2f * x; }

__device__ __forceinline__ uint16_t f2bf1(float f) {
    uint32_t u = __float_as_uint(f);
    return (uint16_t)((u + 0x7fffu + ((u >> 16) & 1u)) >> 16);
}
__device__ __forceinline__ uint16_t f2bf(float f, float* back) {
    uint32_t u = __float_as_uint(f);
    uint32_t r = (u + 0x7fffu + ((u >> 16) & 1u)) >> 16;
    *back = __uint_as_float(r << 16);
    return (uint16_t)r;
}
__device__ __forceinline__ void bf2f2(uint32_t u, float* lo, float* hi) {
    *lo = __uint_as_float(u << 16);
    *hi = __uint_as_float(u & 0xffff0000u);
}

// ---------------- in-degree histogram (scattered atomics only) ----------------
__global__ void k_hist(const int* __restrict__ ei, int* counts) {
    int e = blockIdx.x * blockDim.x + threadIdx.x;
    if (e < N_EDGES) atomicAdd(&counts[ei[N_EDGES + e]], 1);
}

// ---------------- sum of edge_attr: 256 blocks, per-block LDS reduce, 1 atomic/block ----------------
__global__ void k_easum(const float* __restrict__ ea, float* scalars) {
    __shared__ float wsums[4];
    int t = threadIdx.x;
    float v = 0.f;
    for (int e = blockIdx.x * 256 + t; e < N_EDGES; e += 256 * 256) v += ea[e];
    #pragma unroll
    for (int off = 32; off >= 1; off >>= 1) v += __shfl_xor(v, off);
    if ((t & 63) == 0) wsums[t >> 6] = v;
    __syncthreads();
    if (t == 0) atomicAdd(&scalars[25], wsums[0] + wsums[1] + wsums[2] + wsums[3]);
}

// ---------------- we_dot per head + ea_mean ----------------
__global__ void k_wedot(const float* __restrict__ We1, const float* __restrict__ ae1,
                        const float* __restrict__ We2, const float* __restrict__ ae2,
                        float* scalars) {
    int t = threadIdx.x;
    if (t < NH1) {
        float s = 0.f;
        for (int c = 0; c < NC1; c++) s += We1[t * NC1 + c] * ae1[t * NC1 + c];
        scalars[1 + t] = s;
    } else if (t < NH1 + NH2) {
        int h = t - NH1;
        float s = 0.f;
        for (int c = 0; c < NC2; c++) s += We2[h * NC2 + c] * ae2[h * NC2 + c];
        scalars[17 + h] = s;
    } else if (t == 63) {
        scalars[0] = scalars[25] / (float)N_EDGES;   // ea_mean
    }
}

// ---------------- hierarchical scan, stage 1: per-block (1024) scan ----------------
// value scanned = counts[i] + 1  (the +1 is the self loop)
__global__ __launch_bounds__(1024) void k_scan1(const int* __restrict__ counts,
                                                int* rowptr, int* bsums) {
    __shared__ int wsum[16];
    int t = threadIdx.x;
    int lane = t & 63, w = t >> 6;
    int i = blockIdx.x * 1024 + t;
    int v = (i < N_NODES) ? counts[i] + 1 : 0;
    int incl = v;
    #pragma unroll
    for (int off = 1; off < 64; off <<= 1) {
        int u = __shfl_up(incl, off);
        if (lane >= off) incl += u;
    }
    if (lane == 63) wsum[w] = incl;
    __syncthreads();
    int woff = 0;
    #pragma unroll
    for (int k = 0; k < 16; k++) woff += (k < w) ? wsum[k] : 0;
    if (i < N_NODES) rowptr[i] = woff + incl - v;
    if (t == 1023) bsums[blockIdx.x] = woff + incl;
}

// ---------------- scan stage 2: add block prefix, write cursor + rowptr[N] ----------------
__global__ __launch_bounds__(1024) void k_scan2(int* rowptr, int* cursor,
                                                const int* __restrict__ bsums) {
    __shared__ int off_s;
    int b = blockIdx.x, t = threadIdx.x;
    if (t == 0) {
        int o = 0;
        for (int k = 0; k < b; k++) o += bsums[k];
        off_s = o;
        if (b == 48) rowptr[N_NODES] = o + bsums[48];
    }
    __syncthreads();
    int i = b * 1024 + t;
    if (i < N_NODES) {
        int r = rowptr[i] + off_s;
        rowptr[i] = r;
        cursor[i] = r;
    }
}

// ---------------- scatter edges (+self loops) into CSR ----------------
__global__ void k_scatter(const int* __restrict__ ei, const float* __restrict__ ea,
                          const float* __restrict__ scalars, int* cursor,
                          int* csr_src, float* csr_ea) {
    int i = blockIdx.x * blockDim.x + threadIdx.x;
    if (i < N_EDGES) {
        int s = ei[i], d = ei[N_EDGES + i];
        int pos = atomicAdd(&cursor[d], 1);
        csr_src[pos] = s;
        csr_ea[pos] = ea[i];
    } else if (i < N_TOT) {
        int n = i - N_EDGES;
        int pos = atomicAdd(&cursor[n], 1);
        csr_src[pos] = n;
        csr_ea[pos] = scalars[0];
    }
}

// ---------------- fused convert: x -> (xh, xl) [MPAD][KP], W1 -> (whT, wlT) [F1][KP] ----------------
__global__ void k_cvt(const float* __restrict__ x, const float* __restrict__ W1,
                      uint16_t* __restrict__ xh, uint16_t* __restrict__ xl,
                      uint16_t* __restrict__ wht, uint16_t* __restrict__ wlt) {
    int idx = blockIdx.x * 256 + threadIdx.x;
    if (idx < NCVT_X) {
        int row = idx / 28, kw = idx - row * 28;
        int k0 = kw * 8;
        uint16_t hv[8], lv[8];
        #pragma unroll
        for (int j = 0; j < 8; j++) {
            int k = k0 + j;
            float v = (row < N_NODES && k < IN_F) ? x[(size_t)row * IN_F + k] : 0.f;
            float hf;
            hv[j] = f2bf(v, &hf);
            lv[j] = f2bf1(v - hf);
        }
        *(uint4*)(xh + (size_t)row * KP + k0) = *(const uint4*)hv;
        *(uint4*)(xl + (size_t)row * KP + k0) = *(const uint4*)lv;
    } else if (idx < NCVT_X + NCVT_W) {
        int id2 = idx - NCVT_X;
        int col = id2 / 28, kw = id2 - col * 28;
        int k0 = kw * 8;
        uint16_t hv[8], lv[8];
        #pragma unroll
        for (int j = 0; j < 8; j++) {
            int k = k0 + j;
            float v = (k < IN_F) ? W1[(size_t)k * F1 + col] : 0.f;
            float hf;
            hv[j] = f2bf(v, &hf);
            lv[j] = f2bf1(v - hf);
        }
        *(uint4*)(wht + (size_t)col * KP + k0) = *(const uint4*)hv;
        *(uint4*)(wlt + (size_t)col * KP + k0) = *(const uint4*)lv;
    }
}

// ---------------- GEMM1 via MFMA: xl1 = x @ W1, bf16 hi/lo split (3 terms) ----------------
__global__ __launch_bounds__(256) void k_gemm1_mfma(const uint16_t* __restrict__ xh,
        const uint16_t* __restrict__ xl, const uint16_t* __restrict__ wht,
        const uint16_t* __restrict__ wlt, uint16_t* __restrict__ xl1b) {
    __shared__ uint16_t lds[4 * 8 * 64 * 8];   // Ah, Al, Bh, Bl ; 32 KiB
    const int t = threadIdx.x;
    const int l = t & 63, w = t >> 6;
    const int wm = w >> 1, wn = w & 1;
    const int m0 = blockIdx.x * 128;
    const int n0 = blockIdx.y * 128;
    const int lr = l & 15, lk = l >> 4;

    uint16_t* ldsAh = lds;
    uint16_t* ldsAl = lds + 8 * 64 * 8;
    uint16_t* ldsBh = lds + 2 * 8 * 64 * 8;
    uint16_t* ldsBl = lds + 3 * 8 * 64 * 8;

    f32x4 acc[4][4];
    #pragma unroll
    for (int i = 0; i < 4; i++)
        #pragma unroll
        for (int j = 0; j < 4; j++)
            acc[i][j] = (f32x4){0.f, 0.f, 0.f, 0.f};

    for (int ks = 0; ks < 7; ks++) {
        const int kb = ks * 32 + lk * 8;
        #pragma unroll
        for (int ii = 0; ii < 2; ii++) {
            const int f = 2 * w + ii;
            const uint16_t* sAh = xh  + (size_t)(m0 + f * 16 + lr) * KP + kb;
            const uint16_t* sAl = xl  + (size_t)(m0 + f * 16 + lr) * KP + kb;
            const uint16_t* sBh = wht + (size_t)(n0 + f * 16 + lr) * KP + kb;
            const uint16_t* sBl = wlt + (size_t)(n0 + f * 16 + lr) * KP + kb;
            GLL16(sAh, ldsAh + f * 512);
            GLL16(sAl, ldsAl + f * 512);
            GLL16(sBh, ldsBh + f * 512);
            GLL16(sBl, ldsBl + f * 512);
        }
        __syncthreads();
        bf16x8 ah[4], al[4];
        #pragma unroll
        for (int i = 0; i < 4; i++) {
            const int f = wm * 4 + i;
            ah[i] = *(const bf16x8*)(ldsAh + (f * 64 + l) * 8);
            al[i] = *(const bf16x8*)(ldsAl + (f * 64 + l) * 8);
        }
        #pragma unroll
        for (int j = 0; j < 4; j++) {
            const int g = wn * 4 + j;
            bf16x8 bh = *(const bf16x8*)(ldsBh + (g * 64 + l) * 8);
            bf16x8 bl = *(const bf16x8*)(ldsBl + (g * 64 + l) * 8);
            #pragma unroll
            for (int i = 0; i < 4; i++) {
                acc[i][j] = __builtin_amdgcn_mfma_f32_16x16x32_bf16(ah[i], bh, acc[i][j], 0, 0, 0);
                acc[i][j] = __builtin_amdgcn_mfma_f32_16x16x32_bf16(ah[i], bl, acc[i][j], 0, 0, 0);
                acc[i][j] = __builtin_amdgcn_mfma_f32_16x16x32_bf16(al[i], bh, acc[i][j], 0, 0, 0);
            }
        }
        __syncthreads();
    }
    #pragma unroll
    for (int i = 0; i < 4; i++) {
        const int gm_base = m0 + wm * 64 + i * 16 + lk * 4;
        #pragma unroll
        for (int r = 0; r < 4; r++) {
            const int gm = gm_base + r;
            if (gm < N_NODES) {
                #pragma unroll
                for (int j = 0; j < 4; j++) {
                    const int gn = n0 + wn * 64 + j * 16 + lr;
                    xl1b[(size_t)gm * F1 + gn] = f2bf1(acc[i][j][r]);
                }
            }
        }
    }
}

// ---------------- alpha_src1/alpha_dst1 (bf16 xl1) ----------------
__global__ void k_alphas1(const uint16_t* __restrict__ xl1b, const float* __restrict__ a_src,
                          const float* __restrict__ a_dst,
                          float* __restrict__ asrc, float* __restrict__ adst) {
    int idx = blockIdx.x * blockDim.x + threadIdx.x;   // n*16 + h
    if (idx >= N_NODES * NH1) return;
    int h = idx & 15;
    const uint4* xp = (const uint4*)(xl1b + (size_t)idx * 16);
    uint4 u0 = xp[0], u1 = xp[1];
    uint32_t us[8] = {u0.x, u0.y, u0.z, u0.w, u1.x, u1.y, u1.z, u1.w};
    float as = 0.f, ad = 0.f;
    #pragma unroll
    for (int q = 0; q < 8; q++) {
        float lo, hi;
        bf2f2(us[q], &lo, &hi);
        as += lo * a_src[h * 16 + 2 * q] + hi * a_src[h * 16 + 2 * q + 1];
        ad += lo * a_dst[h * 16 + 2 * q] + hi * a_dst[h * 16 + 2 * q + 1];
    }
    asrc[idx] = as;
    adst[idx] = ad;
}

// ---------------- aggregation layer 1 (wave per node, 2x unrolled edge loop) ----------------
__global__ __launch_bounds__(256) void k_agg1(const int* __restrict__ rowptr,
        const int* __restrict__ csr_src, const float* __restrict__ csr_ea,
        const uint16_t* __restrict__ xl1b, const float* __restrict__ asrc,
        const float* __restrict__ adst, const float* __restrict__ scalars,
        const float* __restrict__ b1, uint16_t* __restrict__ h1b) {
    int node = blockIdx.x * 4 + (threadIdx.x >> 6);
    int lane = threadIdx.x & 63;
    int eg = lane >> 4, h = lane & 15;
    int r0 = rowptr[node], r1 = rowptr[node + 1];
    float ad = adst[node * 16 + h];
    float wd = scalars[1 + h];
    float den = 0.f;
    float acc[16];
    #pragma unroll
    for (int c = 0; c < 16; c++) acc[c] = 0.f;
    int j = r0 + eg;
    for (; j + 4 < r1; j += 8) {
        int s0 = csr_src[j], s1 = csr_src[j + 4];
        float e0 = csr_ea[j], e1 = csr_ea[j + 4];
        float p0 = asrc[s0 * 16 + h], p1 = asrc[s1 * 16 + h];
        const uint4* xp0 = (const uint4*)(xl1b + (size_t)s0 * F1 + h * 16);
        const uint4* xp1 = (const uint4*)(xl1b + (size_t)s1 * F1 + h * 16);
        uint4 u0a = xp0[0], u0b = xp0[1];
        uint4 u1a = xp1[0], u1b = xp1[1];
        float w0 = __expf(lrelu(p0 + ad + e0 * wd));
        float w1 = __expf(lrelu(p1 + ad + e1 * wd));
        den += w0 + w1;
        float lo, hi;
        bf2f2(u0a.x, &lo, &hi); acc[0] += w0 * lo;  acc[1] += w0 * hi;
        bf2f2(u0a.y, &lo, &hi); acc[2] += w0 * lo;  acc[3] += w0 * hi;
        bf2f2(u0a.z, &lo, &hi); acc[4] += w0 * lo;  acc[5] += w0 * hi;
        bf2f2(u0a.w, &lo, &hi); acc[6] += w0 * lo;  acc[7] += w0 * hi;
        bf2f2(u0b.x, &lo, &hi); acc[8] += w0 * lo;  acc[9] += w0 * hi;
        bf2f2(u0b.y, &lo, &hi); acc[10] += w0 * lo; acc[11] += w0 * hi;
        bf2f2(u0b.z, &lo, &hi); acc[12] += w0 * lo; acc[13] += w0 * hi;
        bf2f2(u0b.w, &lo, &hi); acc[14] += w0 * lo; acc[15] += w0 * hi;
        bf2f2(u1a.x, &lo, &hi); acc[0] += w1 * lo;  acc[1] += w1 * hi;
        bf2f2(u1a.y, &lo, &hi); acc[2] += w1 * lo;  acc[3] += w1 * hi;
        bf2f2(u1a.z, &lo, &hi); acc[4] += w1 * lo;  acc[5] += w1 * hi;
        bf2f2(u1a.w, &lo, &hi); acc[6] += w1 * lo;  acc[7] += w1 * hi;
        bf2f2(u1b.x, &lo, &hi); acc[8] += w1 * lo;  acc[9] += w1 * hi;
        bf2f2(u1b.y, &lo, &hi); acc[10] += w1 * lo; acc[11] += w1 * hi;
        bf2f2(u1b.z, &lo, &hi); acc[12] += w1 * lo; acc[13] += w1 * hi;
        bf2f2(u1b.w, &lo, &hi); acc[14] += w1 * lo; acc[15] += w1 * hi;
    }
    if (j < r1) {
        int s = csr_src[j];
        float a = lrelu(asrc[s * 16 + h] + ad + csr_ea[j] * wd);
        float wgt = __expf(a);
        den += wgt;
        const uint4* xp = (const uint4*)(xl1b + (size_t)s * F1 + h * 16);
        uint4 u0 = xp[0], u1 = xp[1];
        float lo, hi;
        bf2f2(u0.x, &lo, &hi); acc[0] += wgt * lo;  acc[1] += wgt * hi;
        bf2f2(u0.y, &lo, &hi); acc[2] += wgt * lo;  acc[3] += wgt * hi;
        bf2f2(u0.z, &lo, &hi); acc[4] += wgt * lo;  acc[5] += wgt * hi;
        bf2f2(u0.w, &lo, &hi); acc[6] += wgt * lo;  acc[7] += wgt * hi;
        bf2f2(u1.x, &lo, &hi); acc[8] += wgt * lo;  acc[9] += wgt * hi;
        bf2f2(u1.y, &lo, &hi); acc[10] += wgt * lo; acc[11] += wgt * hi;
        bf2f2(u1.z, &lo, &hi); acc[12] += wgt * lo; acc[13] += wgt * hi;
        bf2f2(u1.w, &lo, &hi); acc[14] += wgt * lo; acc[15] += wgt * hi;
    }
    den += __shfl_xor(den, 16);
    den += __shfl_xor(den, 32);
    float inv = 1.f / (den + 1e-16f);
    #pragma unroll
    for (int c = 0; c < 16; c++) {
        acc[c] += __shfl_xor(acc[c], 16);
        acc[c] += __shfl_xor(acc[c], 32);
    }
    if (eg == 0) {
        uint32_t pk[8];
        #pragma unroll
        for (int q = 0; q < 8; q++) {
            float v0 = acc[2 * q] * inv + b1[h * 16 + 2 * q];
            float v1 = acc[2 * q + 1] * inv + b1[h * 16 + 2 * q + 1];
            v0 = v0 > 0.f ? v0 : expm1f(v0);   // ELU
            v1 = v1 > 0.f ? v1 : expm1f(v1);
            pk[q] = (uint32_t)f2bf1(v0) | ((uint32_t)f2bf1(v1) << 16);
        }
        uint4* op = (uint4*)(h1b + (size_t)node * F1 + h * 16);
        op[0] = make_uint4(pk[0], pk[1], pk[2], pk[3]);
        op[1] = make_uint4(pk[4], pk[5], pk[6], pk[7]);
    }
}

// ---------------- GEMM2: xl2 = h1 @ W2, output bf16 padded [n][8][4] ----------------
__global__ __launch_bounds__(256) void k_gemm2(const uint16_t* __restrict__ h1b,
                                               const float* __restrict__ W2,
                                               uint16_t* __restrict__ xl2b) {
    __shared__ float W2t[F2][260];
    int t = threadIdx.x;
    for (int i = t; i < 256 * F2; i += 256) {
        int k = i / F2, c = i - k * F2;
        W2t[c][k] = W2[i];
    }
    __syncthreads();
    int idx = blockIdx.x * 256 + t;
    if (idx >= N_NODES * F2) return;
    int n = idx / F2, col = idx - n * F2;
    const uint4* hp = (const uint4*)(h1b + (size_t)n * F1);
    float acc = 0.f;
    #pragma unroll 4
    for (int q = 0; q < 32; q++) {
        uint4 u = hp[q];
        const float4* wp = (const float4*)(&W2t[col][q * 8]);
        float4 w0 = wp[0], w1 = wp[1];
        float lo, hi;
        bf2f2(u.x, &lo, &hi); acc += lo * w0.x + hi * w0.y;
        bf2f2(u.y, &lo, &hi); acc += lo * w0.z + hi * w0.w;
        bf2f2(u.z, &lo, &hi); acc += lo * w1.x + hi * w1.y;
        bf2f2(u.w, &lo, &hi); acc += lo * w1.z + hi * w1.w;
    }
    int hh = col / 3, cc = col - hh * 3;
    xl2b[(size_t)n * 32 + hh * 4 + cc] = f2bf1(acc);
}

// ---------------- zero the padded channel of xl2b ----------------
__global__ void k_xl2pad(uint16_t* __restrict__ xl2b) {
    int i = blockIdx.x * 256 + threadIdx.x;    // n*8 + h
    if (i < N_NODES * 8) xl2b[(size_t)i * 4 + 3] = 0;
}

// ---------------- alpha_src2/alpha_dst2 (bf16 xl2) ----------------
__global__ void k_alphas2(const uint16_t* __restrict__ xl2b, const float* __restrict__ a_src,
                          const float* __restrict__ a_dst,
                          float* __restrict__ asrc, float* __restrict__ adst) {
    int idx = blockIdx.x * blockDim.x + threadIdx.x;   // n*8 + h
    if (idx >= N_NODES * NH2) return;
    int h = idx & 7;
    const uint2* xp = (const uint2*)(xl2b + (size_t)idx * 4);
    uint2 u = xp[0];
    float x0, x1, x2, dummy;
    bf2f2(u.x, &x0, &x1);
    bf2f2(u.y, &x2, &dummy);
    asrc[idx] = x0 * a_src[h * 3 + 0] + x1 * a_src[h * 3 + 1] + x2 * a_src[h * 3 + 2];
    adst[idx] = x0 * a_dst[h * 3 + 0] + x1 * a_dst[h * 3 + 1] + x2 * a_dst[h * 3 + 2];
}

// ---------------- aggregation layer 2 (wave per node, mean over heads) ----------------
__global__ __launch_bounds__(256) void k_agg2(const int* __restrict__ rowptr,
        const int* __restrict__ csr_src, const float* __restrict__ csr_ea,
        const uint16_t* __restrict__ xl2b, const float* __restrict__ asrc,
        const float* __restrict__ adst, const float* __restrict__ scalars,
        const float* __restrict__ b2, float* __restrict__ out) {
    int node = blockIdx.x * 4 + (threadIdx.x >> 6);
    int lane = threadIdx.x & 63;
    int eg = lane >> 3, h = lane & 7;
    int r0 = rowptr[node], r1 = rowptr[node + 1];
    float ad = adst[node * 8 + h];
    float wd = scalars[17 + h];
    float den = 0.f, a0 = 0.f, a1 = 0.f, a2 = 0.f;
    for (int j = r0 + eg; j < r1; j += 8) {
        int s = csr_src[j];
        float a = lrelu(asrc[s * 8 + h] + ad + csr_ea[j] * wd);
        float wgt = __expf(a);
        den += wgt;
        const uint2* xp = (const uint2*)(xl2b + ((size_t)s * 8 + h) * 4);
        uint2 u = xp[0];
        float x0, x1, x2, dummy;
        bf2f2(u.x, &x0, &x1);
        bf2f2(u.y, &x2, &dummy);
        a0 += wgt * x0;
        a1 += wgt * x1;
        a2 += wgt * x2;
    }
    den += __shfl_xor(den, 8); den += __shfl_xor(den, 16); den += __shfl_xor(den, 32);
    float inv = 1.f / (den + 1e-16f);
    a0 += __shfl_xor(a0, 8); a0 += __shfl_xor(a0, 16); a0 += __shfl_xor(a0, 32);
    a1 += __shfl_xor(a1, 8); a1 += __shfl_xor(a1, 16); a1 += __shfl_xor(a1, 32);
    a2 += __shfl_xor(a2, 8); a2 += __shfl_xor(a2, 16); a2 += __shfl_xor(a2, 32);
    a0 *= inv; a1 *= inv; a2 *= inv;
    a0 += __shfl_xor(a0, 1); a0 += __shfl_xor(a0, 2); a0 += __shfl_xor(a0, 4);
    a1 += __shfl_xor(a1, 1); a1 += __shfl_xor(a1, 2); a1 += __shfl_xor(a1, 4);
    a2 += __shfl_xor(a2, 1); a2 += __shfl_xor(a2, 2); a2 += __shfl_xor(a2, 4);
    if (lane == 0) {
        float v0 = a0 * 0.125f + b2[0];
        float v1 = a1 * 0.125f + b2[1];
        float v2 = a2 * 0.125f + b2[2];
        out[node * 3 + 0] = v0 > 0.f ? v0 : expm1f(v0);
        out[node * 3 + 1] = v1 > 0.f ? v1 : expm1f(v1);
        out[node * 3 + 2] = v2 > 0.f ? v2 : expm1f(v2);
    }
}

extern "C" void kernel_launch(void* const* d_in, const int* in_sizes, int n_in,
                              void* d_out, int out_size, void* d_ws, size_t ws_size,
                              hipStream_t stream) {
    const float* x       = (const float*)d_in[0];
    const int*   ei      = (const int*)d_in[1];
    const float* ea      = (const float*)d_in[2];
    const float* W1      = (const float*)d_in[3];
    const float* We1     = (const float*)d_in[4];
    const float* a_src1  = (const float*)d_in[5];
    const float* a_dst1  = (const float*)d_in[6];
    const float* a_edge1 = (const float*)d_in[7];
    const float* b1      = (const float*)d_in[8];
    const float* W2      = (const float*)d_in[9];
    const float* We2     = (const float*)d_in[10];
    const float* a_src2  = (const float*)d_in[11];
    const float* a_dst2  = (const float*)d_in[12];
    const float* a_edge2 = (const float*)d_in[13];
    const float* b2      = (const float*)d_in[14];
    float* out = (float*)d_out;

    char* ws = (char*)d_ws;
    size_t off = 0;
    auto alloc = [&](size_t nbytes) -> void* {
        void* p = ws + off;
        off = (off + nbytes + 255) & ~(size_t)255;
        return p;
    };
    uint16_t* xl1b = (uint16_t*)alloc((size_t)N_NODES * F1 * 2);
    uint16_t* h1b  = (uint16_t*)alloc((size_t)N_NODES * F1 * 2);
    float* asrc1   = (float*)alloc((size_t)N_NODES * NH1 * 4);
    float* adst1   = (float*)alloc((size_t)N_NODES * NH1 * 4);
    uint16_t* xl2b = (uint16_t*)alloc((size_t)N_NODES * 32 * 2);
    float* asrc2   = (float*)alloc((size_t)N_NODES * NH2 * 4);
    float* adst2   = (float*)alloc((size_t)N_NODES * NH2 * 4);
    int*   counts  = (int*)alloc((size_t)N_NODES * 4);
    int*   rowptr  = (int*)alloc((size_t)(N_NODES + 1) * 4);
    int*   cursor  = (int*)alloc((size_t)N_NODES * 4);
    int*   bsums   = (int*)alloc(64 * 4);
    int*   csr_src = (int*)alloc((size_t)N_TOT * 4);
    float* csr_ea  = (float*)alloc((size_t)N_TOT * 4);
    float* scalars = (float*)alloc(128);
    uint16_t* wht  = (uint16_t*)alloc((size_t)F1 * KP * 2);
    uint16_t* wlt  = (uint16_t*)alloc((size_t)F1 * KP * 2);
    uint16_t* xh   = (uint16_t*)alloc((size_t)MPAD * KP * 2);
    uint16_t* xlo  = (uint16_t*)alloc((size_t)MPAD * KP * 2);

    hipMemsetAsync(counts, 0, (size_t)N_NODES * 4, stream);
    hipMemsetAsync(scalars, 0, 128, stream);
    hipLaunchKernelGGL(k_hist, dim3((N_EDGES + 255) / 256), dim3(256), 0, stream,
                       ei, counts);
    hipLaunchKernelGGL(k_easum, dim3(256), dim3(256), 0, stream, ea, scalars);
    hipLaunchKernelGGL(k_wedot, dim3(1), dim3(64), 0, stream,
                       We1, a_edge1, We2, a_edge2, scalars);
    hipLaunchKernelGGL(k_scan1, dim3(49), dim3(1024), 0, stream, counts, rowptr, bsums);
    hipLaunchKernelGGL(k_scan2, dim3(49), dim3(1024), 0, stream, rowptr, cursor, bsums);
    hipLaunchKernelGGL(k_scatter, dim3((N_TOT + 255) / 256), dim3(256), 0, stream,
                       ei, ea, scalars, cursor, csr_src, csr_ea);
    hipLaunchKernelGGL(k_cvt, dim3((NCVT_X + NCVT_W + 255) / 256), dim3(256), 0, stream,
                       x, W1, xh, xlo, wht, wlt);
    hipLaunchKernelGGL(k_gemm1_mfma, dim3(MPAD / 128, 2), dim3(256), 0, stream,
                       xh, xlo, wht, wlt, xl1b);
    hipLaunchKernelGGL(k_alphas1, dim3((N_NODES * NH1 + 255) / 256), dim3(256), 0, stream,
                       xl1b, a_src1, a_dst1, asrc1, adst1);
    hipLaunchKernelGGL(k_agg1, dim3(N_NODES / 4), dim3(256), 0, stream,
                       rowptr, csr_src, csr_ea, xl1b, asrc1, adst1, scalars, b1, h1b);
    hipLaunchKernelGGL(k_xl2pad, dim3((N_NODES * 8 + 255) / 256), dim3(256), 0, stream,
                       xl2b);
    hipLaunchKernelGGL(k_gemm2, dim3((N_NODES * F2 + 255) / 256), dim3(256), 0, stream,
                       h1b, W2, xl2b);
    hipLaunchKernelGGL(k_alphas2, dim3((N_NODES * NH2 + 255) / 256), dim3(256), 0, stream,
                       xl2b, a_src2, a_dst2, asrc2, adst2);
    hipLaunchKernelGGL(k_agg2, dim3(N_NODES / 4), dim3(256), 0, stream,
                       rowptr, csr_src, csr_ea, xl2b, asrc2, adst2, scalars, b2, out);
}